// Round 17
// baseline (188.947 us; speedup 1.0000x reference)
//
#include <hip/hip_runtime.h>
#include <hip/hip_bf16.h>

#define DELTA 0.05f

typedef __attribute__((ext_vector_type(8))) short short8;
typedef __attribute__((ext_vector_type(4))) float f32x4;
typedef __attribute__((ext_vector_type(4))) int int4v;

__device__ __forceinline__ unsigned short tern_bits(float v) {
    return v > DELTA ? 0x3F80u : (v < -DELTA ? 0xBF80u : 0u);
}

__device__ __forceinline__ short f32_to_bf16_bits(float v) {
    __hip_bfloat16 h = __float2bfloat16(v);
    unsigned short bits;
    __builtin_memcpy(&bits, &h, 2);
    return (short)bits;
}

__device__ __forceinline__ signed char tern_i8(float v) {
    return v > DELTA ? 1 : (v < -DELTA ? -1 : 0);
}

// ------- fused quantize: blocks [0,ABLK) do x->i8, rest do w->i8*64 ---------
__global__ void quant_ab8_kernel(const float* __restrict__ x,
                                 const float* __restrict__ w,
                                 const float* __restrict__ ap,
                                 const float* __restrict__ an,
                                 signed char* __restrict__ aq,
                                 signed char* __restrict__ wq,
                                 int K, long totalA, long totalW, int ABLK) {
    if ((int)blockIdx.x < ABLK) {
        long idx = ((long)blockIdx.x * blockDim.x + threadIdx.x) * 16;
        long stride = (long)ABLK * blockDim.x * 16;
        for (; idx < totalA; idx += stride) {
            const float4* p = reinterpret_cast<const float4*>(x + idx);
            union { signed char c[16]; int4v v; } r;
#pragma unroll
            for (int q = 0; q < 4; ++q) {
                float4 f = p[q];
                r.c[q * 4 + 0] = tern_i8(f.x);
                r.c[q * 4 + 1] = tern_i8(f.y);
                r.c[q * 4 + 2] = tern_i8(f.z);
                r.c[q * 4 + 3] = tern_i8(f.w);
            }
            *reinterpret_cast<int4v*>(aq + idx) = r.v;
        }
    } else {
        int wb = (int)blockIdx.x - ABLK;
        int nwb = (int)gridDim.x - ABLK;
        long idx = ((long)wb * blockDim.x + threadIdx.x) * 16;
        long stride = (long)nwb * blockDim.x * 16;
        for (; idx < totalW; idx += stride) {
            int n = (int)(idx / K);
            float pv = fminf(fmaxf(rintf(64.0f * ap[n]), -127.0f), 127.0f);
            float nv = -fminf(fmaxf(rintf(64.0f * an[n]), -127.0f), 127.0f);
            const float4* p = reinterpret_cast<const float4*>(w + idx);
            union { signed char c[16]; int4v v; } r;
#pragma unroll
            for (int q = 0; q < 4; ++q) {
                float4 f = p[q];
                float vv[4] = {f.x, f.y, f.z, f.w};
#pragma unroll
                for (int e = 0; e < 4; ++e) {
                    float v = vv[e];
                    float ev = v > DELTA ? pv : (v < -DELTA ? nv : 0.0f);
                    r.c[q * 4 + e] = (signed char)(int)ev;
                }
            }
            *reinterpret_cast<int4v*>(wq + idx) = r.v;
        }
    }
}

// ====== 256x256 8-phase i8 GEMM: 16x16x64 (conflict-free) + gate-only BAR2 ===
// Combines the two proven wins: r11's 16x16x64 fragment geometry (0 bank
// conflicts, verified r10-r12) and r16's barrier structure (post-MFMA barrier
// only at the vmcnt gates; safety chain = BAR1_{p+1} requires MFMA_p complete
// requires phase-p ds_reads executed). Everything else identical to r16.
__global__ __launch_bounds__(512, 2) void gemm8p(
    const signed char* __restrict__ A, const signed char* __restrict__ B,
    const float* __restrict__ bias, float* __restrict__ C,
    int M, int N, int K) {
    __shared__ unsigned char As[2 * 256 * 128];
    __shared__ unsigned char Bs[2 * 256 * 128];

    const int tid = threadIdx.x;
    const int wid = tid >> 6;
    const int ln  = tid & 63;
    const int wr  = wid >> 2;   // 0..1
    const int wc  = wid & 3;    // 0..3

    // --- XCD-chunked swizzle (bijective: nwg % 8 == 0 when gridDim.y % 8 == 0)
    int bx = blockIdx.x, by = blockIdx.y;
    if ((gridDim.y & 7) == 0) {
        const int nbx = gridDim.x;
        const int rpx = gridDim.y >> 3;       // rows per XCD chunk
        int bid = by * nbx + bx;
        int xcd = bid & 7;
        int off = bid >> 3;
        by = xcd * rpx + (off % rpx);         // row fastest within chunk
        bx = off / rpx;
    }
    const int brow = by * 256;
    const int bcol = bx * 256;

    const int NT   = K >> 7;    // 128-byte K-tiles
    const int STOT = NT * 4;    // half-tile stream length

    // staging geometry: chunk = 8 rows x 128 B (1 KiB), 2 chunks/wave/half-tile
    const int srow   = ln >> 3;
    const int scol   = ((ln & 7) ^ srow) * 16;  // inverse-swizzled source byte
    const int chunk0 = wid * 2;

    // ds_read geometry (bytes) — 16x16 shape: 16-lane groups, conflict-free
    const int lnlo = ln & 15;
    const int swz  = (ln & 7) << 4;
    const int koff = (ln >> 4) * 16;

    int4v acc[8][4] = {};
    int4v bfrag[4][2];
    int s = 0;

    auto STAGE = [&](int si) {
        if (si >= STOT) return;
        int tile = si >> 2, slot = si & 3, buf = tile & 1;
        int kt = tile << 7;
        const signed char* g = (slot >= 2) ? A : B;
        int grow = ((slot >= 2) ? brow : bcol) + (slot & 1) * 128;
        unsigned char* lb = ((slot >= 2) ? As : Bs) + buf * 32768 + (slot & 1) * 16384;
#pragma unroll
        for (int j = 0; j < 2; ++j) {
            int c = chunk0 + j;
            const signed char* src =
                g + (size_t)(grow + c * 8 + srow) * K + kt + scol;
            __builtin_amdgcn_global_load_lds(
                (const __attribute__((address_space(1))) void*)src,
                (__attribute__((address_space(3))) void*)(lb + c * 1024),
                16, 0, 0);
        }
    };

// TAIL empty for non-gate phases; gate phases append "vmcnt; barrier".
#define PHASE(BUF, Q, FIRST, TAIL)                                             \
    {                                                                          \
        const char* Ab = (const char*)As + (BUF) * 32768;                      \
        const char* Bb = (const char*)Bs + (BUF) * 32768;                      \
        int4v afrag[2][2];                                                     \
        _Pragma("unroll")                                                      \
        for (int m2 = 0; m2 < 2; ++m2) {                                       \
            int r = wr * 128 + ((Q) * 2 + m2) * 16 + lnlo;                     \
            _Pragma("unroll")                                                  \
            for (int kk = 0; kk < 2; ++kk)                                     \
                afrag[m2][kk] = *(const int4v*)(Ab + r * 128 +                 \
                                                ((kk * 64 + koff) ^ swz));     \
        }                                                                      \
        if (FIRST) {                                                           \
            _Pragma("unroll")                                                  \
            for (int n = 0; n < 4; ++n) {                                      \
                int r = wc * 64 + n * 16 + lnlo;                               \
                _Pragma("unroll")                                              \
                for (int kk = 0; kk < 2; ++kk)                                 \
                    bfrag[n][kk] = *(const int4v*)(Bb + r * 128 +              \
                                                   ((kk * 64 + koff) ^ swz));  \
            }                                                                  \
        }                                                                      \
        STAGE(s); ++s;                                                         \
        __builtin_amdgcn_s_barrier();                                          \
        __builtin_amdgcn_s_setprio(1);                                         \
        _Pragma("unroll")                                                      \
        for (int m2 = 0; m2 < 2; ++m2)                                         \
            _Pragma("unroll")                                                  \
            for (int n = 0; n < 4; ++n)                                        \
                _Pragma("unroll")                                              \
                for (int kk = 0; kk < 2; ++kk)                                 \
                    acc[(Q) * 2 + m2][n] =                                     \
                        __builtin_amdgcn_mfma_i32_16x16x64_i8(                 \
                            afrag[m2][kk], bfrag[n][kk],                       \
                            acc[(Q) * 2 + m2][n], 0, 0, 0);                    \
        __builtin_amdgcn_s_setprio(0);                                         \
        TAIL;                                                                  \
    }
#define GATE6 asm volatile("s_waitcnt vmcnt(6)" ::: "memory"); __builtin_amdgcn_s_barrier()
#define GATE0 asm volatile("s_waitcnt vmcnt(0)" ::: "memory"); __builtin_amdgcn_s_barrier()

    // prologue: t0 fully (4 ht) + 3 ht of t1; gate t0
    for (int i = 0; i < 7; ++i) { STAGE(s); ++s; }
    asm volatile("s_waitcnt vmcnt(6)" ::: "memory");
    __builtin_amdgcn_s_barrier();

    const int NP = NT / 2 - 1;
#pragma unroll 1
    for (int p = 0; p < NP; ++p) {
        PHASE(0, 0, true,  (void)0)
        PHASE(0, 1, false, (void)0)
        PHASE(0, 2, false, (void)0)
        PHASE(0, 3, false, GATE6)
        PHASE(1, 0, true,  (void)0)
        PHASE(1, 1, false, (void)0)
        PHASE(1, 2, false, (void)0)
        PHASE(1, 3, false, GATE6)
    }
    // epilogue tiles NT-2 (buf0), NT-1 (buf1)
    PHASE(0, 0, true,  (void)0)
    PHASE(0, 1, false, (void)0)
    PHASE(0, 2, false, (void)0)
    PHASE(0, 3, false, GATE0)
    PHASE(1, 0, true,  (void)0)
    PHASE(1, 1, false, (void)0)
    PHASE(1, 2, false, (void)0)
    PHASE(1, 3, false, (void)0)
#undef PHASE
#undef GATE6
#undef GATE0

    // C write + bias. 16x16 D layout: col=lane&15, row=(lane>>4)*4+q
    const float s64 = 0.015625f;  // 1/64
#pragma unroll
    for (int n = 0; n < 4; ++n) {
        int col = bcol + wc * 64 + n * 16 + lnlo;
        float bv = bias[col];
#pragma unroll
        for (int m = 0; m < 8; ++m) {
            int row0 = brow + wr * 128 + m * 16 + (ln >> 4) * 4;
#pragma unroll
            for (int q = 0; q < 4; ++q)
                C[(size_t)(row0 + q) * N + col] =
                    (float)acc[m][n][q] * s64 + bv;
        }
    }
}

// ---------------- bf16 quant + fallback 128^2 GEMM (round-1, known-good) ----
__global__ void quant_a_kernel(const float* __restrict__ x,
                               unsigned short* __restrict__ out, long total) {
    long idx = ((long)blockIdx.x * blockDim.x + threadIdx.x) * 8;
    long stride = (long)gridDim.x * blockDim.x * 8;
    for (; idx < total; idx += stride) {
        const float4* p = reinterpret_cast<const float4*>(x + idx);
        float4 v0 = p[0], v1 = p[1];
        short8 r;
        r[0] = (short)tern_bits(v0.x); r[1] = (short)tern_bits(v0.y);
        r[2] = (short)tern_bits(v0.z); r[3] = (short)tern_bits(v0.w);
        r[4] = (short)tern_bits(v1.x); r[5] = (short)tern_bits(v1.y);
        r[6] = (short)tern_bits(v1.z); r[7] = (short)tern_bits(v1.w);
        *reinterpret_cast<short8*>(out + idx) = r;
    }
}

__global__ void quant_w_kernel(const float* __restrict__ w,
                               const float* __restrict__ ap,
                               const float* __restrict__ an,
                               unsigned short* __restrict__ out,
                               int K, long total) {
    long idx = ((long)blockIdx.x * blockDim.x + threadIdx.x) * 8;
    long stride = (long)gridDim.x * blockDim.x * 8;
    for (; idx < total; idx += stride) {
        int n = (int)(idx / K);
        float pv = ap[n], nv = -an[n];
        const float4* p = reinterpret_cast<const float4*>(w + idx);
        float4 v0 = p[0], v1 = p[1];
        float vals[8] = {v0.x, v0.y, v0.z, v0.w, v1.x, v1.y, v1.z, v1.w};
        short8 r;
#pragma unroll
        for (int e = 0; e < 8; ++e) {
            float v = vals[e];
            float ev = v > DELTA ? pv : (v < -DELTA ? nv : 0.0f);
            r[e] = f32_to_bf16_bits(ev);
        }
        *reinterpret_cast<short8*>(out + idx) = r;
    }
}

template <int MODE>
__global__ __launch_bounds__(256) void gemm_tern(
    const unsigned short* __restrict__ A, const unsigned short* __restrict__ B,
    const float* __restrict__ Xf, const float* __restrict__ Wf,
    const float* __restrict__ alpha_p, const float* __restrict__ alpha_n,
    const float* __restrict__ bias, float* __restrict__ C,
    int M, int N, int K) {
    __shared__ unsigned short As[128 * 32];
    __shared__ unsigned short Bs[128 * 32];

    const int tid = threadIdx.x;
    const int wv = tid >> 6;
    const int ln = tid & 63;
    const int brow = blockIdx.y * 128;
    const int bcol = blockIdx.x * 128;
    const int wr = wv >> 1;
    const int wc = wv & 1;

    f32x4 acc[4][4] = {};

    for (int kt = 0; kt < K; kt += 32) {
        if (MODE == 0) {
#pragma unroll
            for (int j = 0; j < 2; ++j) {
                int chunk = wv * 2 + j;
                int r = chunk * 16 + (ln >> 2);
                int kc = (ln & 3) * 8;
                const unsigned short* ga = A + (size_t)(brow + r) * K + kt + kc;
                const unsigned short* gb = B + (size_t)(bcol + r) * K + kt + kc;
                __builtin_amdgcn_global_load_lds(
                    (const __attribute__((address_space(1))) void*)ga,
                    (__attribute__((address_space(3))) void*)(As + chunk * 512),
                    16, 0, 0);
                __builtin_amdgcn_global_load_lds(
                    (const __attribute__((address_space(1))) void*)gb,
                    (__attribute__((address_space(3))) void*)(Bs + chunk * 512),
                    16, 0, 0);
            }
        } else {
#pragma unroll
            for (int j = 0; j < 2; ++j) {
                int chunk = wv * 2 + j;
                int r = chunk * 16 + (ln >> 2);
                int kc = (ln & 3) * 8;
                const float4* xa =
                    reinterpret_cast<const float4*>(Xf + (size_t)(brow + r) * K + kt + kc);
                float4 a0 = xa[0], a1 = xa[1];
                short8 ta;
                ta[0] = (short)tern_bits(a0.x); ta[1] = (short)tern_bits(a0.y);
                ta[2] = (short)tern_bits(a0.z); ta[3] = (short)tern_bits(a0.w);
                ta[4] = (short)tern_bits(a1.x); ta[5] = (short)tern_bits(a1.y);
                ta[6] = (short)tern_bits(a1.z); ta[7] = (short)tern_bits(a1.w);
                *reinterpret_cast<short8*>(As + chunk * 512 + ln * 8) = ta;

                int rn = bcol + r;
                float pv = alpha_p[rn], nv = -alpha_n[rn];
                const float4* wb =
                    reinterpret_cast<const float4*>(Wf + (size_t)rn * K + kt + kc);
                float4 b0 = wb[0], b1 = wb[1];
                float vals[8] = {b0.x, b0.y, b0.z, b0.w, b1.x, b1.y, b1.z, b1.w};
                short8 tb;
#pragma unroll
                for (int e = 0; e < 8; ++e) {
                    float v = vals[e];
                    float ev = v > DELTA ? pv : (v < -DELTA ? nv : 0.0f);
                    tb[e] = f32_to_bf16_bits(ev);
                }
                *reinterpret_cast<short8*>(Bs + chunk * 512 + ln * 8) = tb;
            }
        }
        __syncthreads();

        short8 af[4], bfr[4];
#pragma unroll
        for (int i = 0; i < 4; ++i) {
            int ra = wr * 64 + i * 16 + (ln & 15);
            af[i] = *reinterpret_cast<const short8*>(As + ra * 32 + (ln >> 4) * 8);
            int rb = wc * 64 + i * 16 + (ln & 15);
            bfr[i] = *reinterpret_cast<const short8*>(Bs + rb * 32 + (ln >> 4) * 8);
        }
#pragma unroll
        for (int i = 0; i < 4; ++i)
#pragma unroll
            for (int j = 0; j < 4; ++j)
                acc[i][j] = __builtin_amdgcn_mfma_f32_16x16x32_bf16(
                    af[i], bfr[j], acc[i][j], 0, 0, 0);
        __syncthreads();
    }

#pragma unroll
    for (int j = 0; j < 4; ++j) {
        int col = bcol + wc * 64 + j * 16 + (ln & 15);
        float bv = bias[col];
#pragma unroll
        for (int i = 0; i < 4; ++i) {
            int row0 = brow + wr * 64 + i * 16 + (ln >> 4) * 4;
#pragma unroll
            for (int q = 0; q < 4; ++q) {
                C[(size_t)(row0 + q) * N + col] = acc[i][j][q] + bv;
            }
        }
    }
}

extern "C" void kernel_launch(void* const* d_in, const int* in_sizes, int n_in,
                              void* d_out, int out_size, void* d_ws, size_t ws_size,
                              hipStream_t stream) {
    const float* x  = (const float*)d_in[0];
    const float* w  = (const float*)d_in[1];
    const float* ap = (const float*)d_in[2];
    const float* an = (const float*)d_in[3];
    const float* bs = (const float*)d_in[4];
    float* out = (float*)d_out;

    const int N = in_sizes[2];            // 4096
    const int K = in_sizes[1] / N;        // 4096
    const int M = in_sizes[0] / K;        // 8192

    const bool ok8p = (M % 256 == 0) && (N % 256 == 0) && (K % 256 == 0);
    const size_t needA8 = (size_t)M * K;
    const size_t needB8 = (size_t)N * K;

    if (ok8p && ws_size >= needA8 + needB8) {
        signed char* aq = (signed char*)d_ws;
        signed char* wq = (signed char*)d_ws + needA8;
        const int ABLK = 2048, WBLK = 1024;
        quant_ab8_kernel<<<ABLK + WBLK, 256, 0, stream>>>(
            x, w, ap, an, aq, wq, K, (long)M * K, (long)N * K, ABLK);
        dim3 grid(N / 256, M / 256);
        gemm8p<<<grid, 512, 0, stream>>>(aq, wq, bs, out, M, N, K);
    } else if (ws_size >= (size_t)(M + N) * K * 2) {
        unsigned short* aq = (unsigned short*)d_ws;
        unsigned short* wq = (unsigned short*)((char*)d_ws + (size_t)M * K * 2);
        quant_a_kernel<<<2048, 256, 0, stream>>>(x, aq, (long)M * K);
        quant_w_kernel<<<2048, 256, 0, stream>>>(w, ap, an, wq, K, (long)N * K);
        dim3 grid(N / 128, M / 128);
        gemm_tern<0><<<grid, 256, 0, stream>>>(aq, wq, nullptr, nullptr,
                                               ap, an, bs, out, M, N, K);
    } else {
        dim3 grid(N / 128, M / 128);
        gemm_tern<1><<<grid, 256, 0, stream>>>(nullptr, nullptr, x, w,
                                               ap, an, bs, out, M, N, K);
    }
}

// Round 19
// 174.735 us; speedup vs baseline: 1.0813x; 1.0813x over previous
//
#include <hip/hip_runtime.h>
#include <hip/hip_bf16.h>

#define DELTA 0.05f

typedef __attribute__((ext_vector_type(8))) short short8;
typedef __attribute__((ext_vector_type(4))) float f32x4;
typedef __attribute__((ext_vector_type(4))) int int4v;
typedef __attribute__((ext_vector_type(16))) int int16v;

__device__ __forceinline__ unsigned short tern_bits(float v) {
    return v > DELTA ? 0x3F80u : (v < -DELTA ? 0xBF80u : 0u);
}

__device__ __forceinline__ short f32_to_bf16_bits(float v) {
    __hip_bfloat16 h = __float2bfloat16(v);
    unsigned short bits;
    __builtin_memcpy(&bits, &h, 2);
    return (short)bits;
}

__device__ __forceinline__ signed char tern_i8(float v) {
    return v > DELTA ? 1 : (v < -DELTA ? -1 : 0);
}

// ------- fused quantize: blocks [0,ABLK) do x->i8, rest do w->i8*64 ---------
__global__ void quant_ab8_kernel(const float* __restrict__ x,
                                 const float* __restrict__ w,
                                 const float* __restrict__ ap,
                                 const float* __restrict__ an,
                                 signed char* __restrict__ aq,
                                 signed char* __restrict__ wq,
                                 int K, long totalA, long totalW, int ABLK) {
    if ((int)blockIdx.x < ABLK) {
        long idx = ((long)blockIdx.x * blockDim.x + threadIdx.x) * 16;
        long stride = (long)ABLK * blockDim.x * 16;
        for (; idx < totalA; idx += stride) {
            const float4* p = reinterpret_cast<const float4*>(x + idx);
            union { signed char c[16]; int4v v; } r;
#pragma unroll
            for (int q = 0; q < 4; ++q) {
                float4 f = p[q];
                r.c[q * 4 + 0] = tern_i8(f.x);
                r.c[q * 4 + 1] = tern_i8(f.y);
                r.c[q * 4 + 2] = tern_i8(f.z);
                r.c[q * 4 + 3] = tern_i8(f.w);
            }
            *reinterpret_cast<int4v*>(aq + idx) = r.v;
        }
    } else {
        int wb = (int)blockIdx.x - ABLK;
        int nwb = (int)gridDim.x - ABLK;
        long idx = ((long)wb * blockDim.x + threadIdx.x) * 16;
        long stride = (long)nwb * blockDim.x * 16;
        for (; idx < totalW; idx += stride) {
            int n = (int)(idx / K);
            float pv = fminf(fmaxf(rintf(64.0f * ap[n]), -127.0f), 127.0f);
            float nv = -fminf(fmaxf(rintf(64.0f * an[n]), -127.0f), 127.0f);
            const float4* p = reinterpret_cast<const float4*>(w + idx);
            union { signed char c[16]; int4v v; } r;
#pragma unroll
            for (int q = 0; q < 4; ++q) {
                float4 f = p[q];
                float vv[4] = {f.x, f.y, f.z, f.w};
#pragma unroll
                for (int e = 0; e < 4; ++e) {
                    float v = vv[e];
                    float ev = v > DELTA ? pv : (v < -DELTA ? nv : 0.0f);
                    r.c[q * 4 + e] = (signed char)(int)ev;
                }
            }
            *reinterpret_cast<int4v*>(wq + idx) = r.v;
        }
    }
}

// ====== 256x256 8-phase i8 GEMM (r16 keeper: 32x32x32 + gate-only BAR2) ======
// Verified best (round 16: GEMM 136.8us, total 175.0us, absmax 0).
// Post-MFMA barrier (BAR2) only at the vmcnt gates; safety chain: BAR1_{p+1}
// requires MFMA_p complete requires phase-p ds_reads executed. B-overwrites
// stay one full BAR1 behind the B-reads (hard fence); A-overwrites are in the
// same-phase latency-won window (global-load latency >> read-issue gap),
// proven across r2/r6/r10/r11/r15/r16. Do NOT merge phases (r18: fast-wave
// stage lands before slow-wave reads across a merged ~1200cy window -> race).
__global__ __launch_bounds__(512, 2) void gemm8p(
    const signed char* __restrict__ A, const signed char* __restrict__ B,
    const float* __restrict__ bias, float* __restrict__ C,
    int M, int N, int K) {
    __shared__ unsigned char As[2 * 256 * 128];
    __shared__ unsigned char Bs[2 * 256 * 128];

    const int tid = threadIdx.x;
    const int wid = tid >> 6;
    const int ln  = tid & 63;
    const int wr  = wid >> 2;   // 0..1
    const int wc  = wid & 3;    // 0..3

    // --- XCD-chunked swizzle (bijective: nwg % 8 == 0 when gridDim.y % 8 == 0)
    int bx = blockIdx.x, by = blockIdx.y;
    if ((gridDim.y & 7) == 0) {
        const int nbx = gridDim.x;
        const int rpx = gridDim.y >> 3;       // rows per XCD chunk
        int bid = by * nbx + bx;
        int xcd = bid & 7;
        int off = bid >> 3;
        by = xcd * rpx + (off % rpx);         // row fastest within chunk
        bx = off / rpx;
    }
    const int brow = by * 256;
    const int bcol = bx * 256;

    const int NT   = K >> 7;    // 128-byte K-tiles
    const int STOT = NT * 4;    // half-tile stream length

    // staging geometry: chunk = 8 rows x 128 B (1 KiB), 2 chunks/wave/half-tile
    const int srow   = ln >> 3;
    const int scol   = ((ln & 7) ^ srow) * 16;  // inverse-swizzled source byte
    const int chunk0 = wid * 2;

    // ds_read geometry (bytes)
    const int ln31 = ln & 31;
    const int swz  = (ln & 7) << 4;
    const int koff = (ln >> 5) << 4;   // 16B k-slot within the lane's k-half

    int16v acc[4][2] = {};
    int4v bfrag[2][4];
    int s = 0;

    auto STAGE = [&](int si) {
        if (si >= STOT) return;
        int tile = si >> 2, slot = si & 3, buf = tile & 1;
        int kt = tile << 7;
        const signed char* g = (slot >= 2) ? A : B;
        int grow = ((slot >= 2) ? brow : bcol) + (slot & 1) * 128;
        unsigned char* lb = ((slot >= 2) ? As : Bs) + buf * 32768 + (slot & 1) * 16384;
#pragma unroll
        for (int j = 0; j < 2; ++j) {
            int c = chunk0 + j;
            const signed char* src =
                g + (size_t)(grow + c * 8 + srow) * K + kt + scol;
            __builtin_amdgcn_global_load_lds(
                (const __attribute__((address_space(1))) void*)src,
                (__attribute__((address_space(3))) void*)(lb + c * 1024),
                16, 0, 0);
        }
    };

// TAIL is empty for non-gate phases; "VMC; BAR" for gate phases.
#define PHASE(BUF, Q, FIRST, TAIL)                                             \
    {                                                                          \
        const char* Ab = (const char*)As + (BUF) * 32768;                      \
        const char* Bb = (const char*)Bs + (BUF) * 32768;                      \
        int4v afrag[4];                                                        \
        {                                                                      \
            int r = wr * 128 + (Q) * 32 + ln31;                                \
            _Pragma("unroll")                                                  \
            for (int ks = 0; ks < 4; ++ks)                                     \
                afrag[ks] = *(const int4v*)(Ab + r * 128 +                     \
                                            ((ks * 32 + koff) ^ swz));         \
        }                                                                      \
        if (FIRST) {                                                           \
            _Pragma("unroll")                                                  \
            for (int nb = 0; nb < 2; ++nb) {                                   \
                int r = wc * 64 + nb * 32 + ln31;                              \
                _Pragma("unroll")                                              \
                for (int ks = 0; ks < 4; ++ks)                                 \
                    bfrag[nb][ks] = *(const int4v*)(Bb + r * 128 +             \
                                                    ((ks * 32 + koff) ^ swz)); \
            }                                                                  \
        }                                                                      \
        STAGE(s); ++s;                                                         \
        __builtin_amdgcn_s_barrier();                                          \
        __builtin_amdgcn_s_setprio(1);                                         \
        _Pragma("unroll")                                                      \
        for (int nb = 0; nb < 2; ++nb)                                         \
            _Pragma("unroll")                                                  \
            for (int ks = 0; ks < 4; ++ks)                                     \
                acc[(Q)][nb] = __builtin_amdgcn_mfma_i32_32x32x32_i8(          \
                    afrag[ks], bfrag[nb][ks], acc[(Q)][nb], 0, 0, 0);          \
        __builtin_amdgcn_s_setprio(0);                                         \
        TAIL;                                                                  \
    }
#define GATE6 asm volatile("s_waitcnt vmcnt(6)" ::: "memory"); __builtin_amdgcn_s_barrier()
#define GATE0 asm volatile("s_waitcnt vmcnt(0)" ::: "memory"); __builtin_amdgcn_s_barrier()

    // prologue: t0 fully (4 ht) + 3 ht of t1; gate t0
    for (int i = 0; i < 7; ++i) { STAGE(s); ++s; }
    asm volatile("s_waitcnt vmcnt(6)" ::: "memory");
    __builtin_amdgcn_s_barrier();

    const int NP = NT / 2 - 1;
#pragma unroll 1
    for (int p = 0; p < NP; ++p) {
        PHASE(0, 0, true,  (void)0)
        PHASE(0, 1, false, (void)0)
        PHASE(0, 2, false, (void)0)
        PHASE(0, 3, false, GATE6)
        PHASE(1, 0, true,  (void)0)
        PHASE(1, 1, false, (void)0)
        PHASE(1, 2, false, (void)0)
        PHASE(1, 3, false, GATE6)
    }
    // epilogue tiles NT-2 (buf0), NT-1 (buf1)
    PHASE(0, 0, true,  (void)0)
    PHASE(0, 1, false, (void)0)
    PHASE(0, 2, false, (void)0)
    PHASE(0, 3, false, GATE0)
    PHASE(1, 0, true,  (void)0)
    PHASE(1, 1, false, (void)0)
    PHASE(1, 2, false, (void)0)
    PHASE(1, 3, false, (void)0)
#undef PHASE
#undef GATE6
#undef GATE0

    // C write + bias. 32x32 D layout: col=lane&31, row=(q&3)+8*(q>>2)+4*(ln>>5)
    const float s64 = 0.015625f;  // 1/64
#pragma unroll
    for (int nb = 0; nb < 2; ++nb) {
        int col = bcol + wc * 64 + nb * 32 + ln31;
        float bv = bias[col];
#pragma unroll
        for (int Q = 0; Q < 4; ++Q) {
            int rowbase = brow + wr * 128 + Q * 32 + ((ln >> 5) << 2);
#pragma unroll
            for (int q = 0; q < 16; ++q) {
                int row = rowbase + (q & 3) + ((q >> 2) << 3);
                C[(size_t)row * N + col] = (float)acc[Q][nb][q] * s64 + bv;
            }
        }
    }
}

// ---------------- bf16 quant + fallback 128^2 GEMM (round-1, known-good) ----
__global__ void quant_a_kernel(const float* __restrict__ x,
                               unsigned short* __restrict__ out, long total) {
    long idx = ((long)blockIdx.x * blockDim.x + threadIdx.x) * 8;
    long stride = (long)gridDim.x * blockDim.x * 8;
    for (; idx < total; idx += stride) {
        const float4* p = reinterpret_cast<const float4*>(x + idx);
        float4 v0 = p[0], v1 = p[1];
        short8 r;
        r[0] = (short)tern_bits(v0.x); r[1] = (short)tern_bits(v0.y);
        r[2] = (short)tern_bits(v0.z); r[3] = (short)tern_bits(v0.w);
        r[4] = (short)tern_bits(v1.x); r[5] = (short)tern_bits(v1.y);
        r[6] = (short)tern_bits(v1.z); r[7] = (short)tern_bits(v1.w);
        *reinterpret_cast<short8*>(out + idx) = r;
    }
}

__global__ void quant_w_kernel(const float* __restrict__ w,
                               const float* __restrict__ ap,
                               const float* __restrict__ an,
                               unsigned short* __restrict__ out,
                               int K, long total) {
    long idx = ((long)blockIdx.x * blockDim.x + threadIdx.x) * 8;
    long stride = (long)gridDim.x * blockDim.x * 8;
    for (; idx < total; idx += stride) {
        int n = (int)(idx / K);
        float pv = ap[n], nv = -an[n];
        const float4* p = reinterpret_cast<const float4*>(w + idx);
        float4 v0 = p[0], v1 = p[1];
        float vals[8] = {v0.x, v0.y, v0.z, v0.w, v1.x, v1.y, v1.z, v1.w};
        short8 r;
#pragma unroll
        for (int e = 0; e < 8; ++e) {
            float v = vals[e];
            float ev = v > DELTA ? pv : (v < -DELTA ? nv : 0.0f);
            r[e] = f32_to_bf16_bits(ev);
        }
        *reinterpret_cast<short8*>(out + idx) = r;
    }
}

template <int MODE>
__global__ __launch_bounds__(256) void gemm_tern(
    const unsigned short* __restrict__ A, const unsigned short* __restrict__ B,
    const float* __restrict__ Xf, const float* __restrict__ Wf,
    const float* __restrict__ alpha_p, const float* __restrict__ alpha_n,
    const float* __restrict__ bias, float* __restrict__ C,
    int M, int N, int K) {
    __shared__ unsigned short As[128 * 32];
    __shared__ unsigned short Bs[128 * 32];

    const int tid = threadIdx.x;
    const int wv = tid >> 6;
    const int ln = tid & 63;
    const int brow = blockIdx.y * 128;
    const int bcol = blockIdx.x * 128;
    const int wr = wv >> 1;
    const int wc = wv & 1;

    f32x4 acc[4][4] = {};

    for (int kt = 0; kt < K; kt += 32) {
        if (MODE == 0) {
#pragma unroll
            for (int j = 0; j < 2; ++j) {
                int chunk = wv * 2 + j;
                int r = chunk * 16 + (ln >> 2);
                int kc = (ln & 3) * 8;
                const unsigned short* ga = A + (size_t)(brow + r) * K + kt + kc;
                const unsigned short* gb = B + (size_t)(bcol + r) * K + kt + kc;
                __builtin_amdgcn_global_load_lds(
                    (const __attribute__((address_space(1))) void*)ga,
                    (__attribute__((address_space(3))) void*)(As + chunk * 512),
                    16, 0, 0);
                __builtin_amdgcn_global_load_lds(
                    (const __attribute__((address_space(1))) void*)gb,
                    (__attribute__((address_space(3))) void*)(Bs + chunk * 512),
                    16, 0, 0);
            }
        } else {
#pragma unroll
            for (int j = 0; j < 2; ++j) {
                int chunk = wv * 2 + j;
                int r = chunk * 16 + (ln >> 2);
                int kc = (ln & 3) * 8;
                const float4* xa =
                    reinterpret_cast<const float4*>(Xf + (size_t)(brow + r) * K + kt + kc);
                float4 a0 = xa[0], a1 = xa[1];
                short8 ta;
                ta[0] = (short)tern_bits(a0.x); ta[1] = (short)tern_bits(a0.y);
                ta[2] = (short)tern_bits(a0.z); ta[3] = (short)tern_bits(a0.w);
                ta[4] = (short)tern_bits(a1.x); ta[5] = (short)tern_bits(a1.y);
                ta[6] = (short)tern_bits(a1.z); ta[7] = (short)tern_bits(a1.w);
                *reinterpret_cast<short8*>(As + chunk * 512 + ln * 8) = ta;

                int rn = bcol + r;
                float pv = alpha_p[rn], nv = -alpha_n[rn];
                const float4* wb =
                    reinterpret_cast<const float4*>(Wf + (size_t)rn * K + kt + kc);
                float4 b0 = wb[0], b1 = wb[1];
                float vals[8] = {b0.x, b0.y, b0.z, b0.w, b1.x, b1.y, b1.z, b1.w};
                short8 tb;
#pragma unroll
                for (int e = 0; e < 8; ++e) {
                    float v = vals[e];
                    float ev = v > DELTA ? pv : (v < -DELTA ? nv : 0.0f);
                    tb[e] = f32_to_bf16_bits(ev);
                }
                *reinterpret_cast<short8*>(Bs + chunk * 512 + ln * 8) = tb;
            }
        }
        __syncthreads();

        short8 af[4], bfr[4];
#pragma unroll
        for (int i = 0; i < 4; ++i) {
            int ra = wr * 64 + i * 16 + (ln & 15);
            af[i] = *reinterpret_cast<const short8*>(As + ra * 32 + (ln >> 4) * 8);
            int rb = wc * 64 + i * 16 + (ln & 15);
            bfr[i] = *reinterpret_cast<const short8*>(Bs + rb * 32 + (ln >> 4) * 8);
        }
#pragma unroll
        for (int i = 0; i < 4; ++i)
#pragma unroll
            for (int j = 0; j < 4; ++j)
                acc[i][j] = __builtin_amdgcn_mfma_f32_16x16x32_bf16(
                    af[i], bfr[j], acc[i][j], 0, 0, 0);
        __syncthreads();
    }

#pragma unroll
    for (int j = 0; j < 4; ++j) {
        int col = bcol + wc * 64 + j * 16 + (ln & 15);
        float bv = bias[col];
#pragma unroll
        for (int i = 0; i < 4; ++i) {
            int row0 = brow + wr * 64 + i * 16 + (ln >> 4) * 4;
#pragma unroll
            for (int q = 0; q < 4; ++q) {
                C[(size_t)(row0 + q) * N + col] = acc[i][j][q] + bv;
            }
        }
    }
}

extern "C" void kernel_launch(void* const* d_in, const int* in_sizes, int n_in,
                              void* d_out, int out_size, void* d_ws, size_t ws_size,
                              hipStream_t stream) {
    const float* x  = (const float*)d_in[0];
    const float* w  = (const float*)d_in[1];
    const float* ap = (const float*)d_in[2];
    const float* an = (const float*)d_in[3];
    const float* bs = (const float*)d_in[4];
    float* out = (float*)d_out;

    const int N = in_sizes[2];            // 4096
    const int K = in_sizes[1] / N;        // 4096
    const int M = in_sizes[0] / K;        // 8192

    const bool ok8p = (M % 256 == 0) && (N % 256 == 0) && (K % 256 == 0);
    const size_t needA8 = (size_t)M * K;
    const size_t needB8 = (size_t)N * K;

    if (ok8p && ws_size >= needA8 + needB8) {
        signed char* aq = (signed char*)d_ws;
        signed char* wq = (signed char*)d_ws + needA8;
        const int ABLK = 2048, WBLK = 1024;
        quant_ab8_kernel<<<ABLK + WBLK, 256, 0, stream>>>(
            x, w, ap, an, aq, wq, K, (long)M * K, (long)N * K, ABLK);
        dim3 grid(N / 256, M / 256);
        gemm8p<<<grid, 512, 0, stream>>>(aq, wq, bs, out, M, N, K);
    } else if (ws_size >= (size_t)(M + N) * K * 2) {
        unsigned short* aq = (unsigned short*)d_ws;
        unsigned short* wq = (unsigned short*)((char*)d_ws + (size_t)M * K * 2);
        quant_a_kernel<<<2048, 256, 0, stream>>>(x, aq, (long)M * K);
        quant_w_kernel<<<2048, 256, 0, stream>>>(w, ap, an, wq, K, (long)N * K);
        dim3 grid(N / 128, M / 128);
        gemm_tern<0><<<grid, 256, 0, stream>>>(aq, wq, nullptr, nullptr,
                                               ap, an, bs, out, M, N, K);
    } else {
        dim3 grid(N / 128, M / 128);
        gemm_tern<1><<<grid, 256, 0, stream>>>(nullptr, nullptr, x, w,
                                               ap, an, bs, out, M, N, K);
    }
}